// Round 2
// baseline (1091.407 us; speedup 1.0000x reference)
//
#include <hip/hip_runtime.h>
#include <hip/hip_bf16.h>

#define NNODE 10000
#define NEDGE 320000

typedef __attribute__((ext_vector_type(8))) short bf16x8;
typedef __attribute__((ext_vector_type(4))) float f32x4;

__device__ __forceinline__ float sigf(float v){
    return __fdividef(1.f, 1.f + __expf(-v));
}

// ---------------- CSR build ----------------

__global__ __launch_bounds__(256) void k_hist(const int* __restrict__ dst, int* __restrict__ cnt){
    int e = blockIdx.x*256 + threadIdx.x;
    if (e < NEDGE) atomicAdd(&cnt[dst[e]], 1);
}

// single block, 256 threads: exclusive prefix over cnt -> row_ptr, plus dis = rsqrt(deg+1)
__global__ __launch_bounds__(256) void k_scan(const int* __restrict__ cnt, int* __restrict__ row_ptr,
                                              float* __restrict__ dis){
    __shared__ int wsum[4];
    int tid = threadIdx.x;
    int lane = tid & 63, wave = tid >> 6;
    int run = 0;
    if (tid == 0) row_ptr[0] = 0;
    for (int base = 0; base < NNODE; base += 256){
        int i = base + tid;
        int v = (i < NNODE) ? cnt[i] : 0;
        if (i < NNODE) dis[i] = rsqrtf((float)v + 1.0f);
        int sv = v;
        #pragma unroll
        for (int off = 1; off < 64; off <<= 1){
            int t = __shfl_up(sv, off);
            if (lane >= off) sv += t;
        }
        if (lane == 63) wsum[wave] = sv;
        __syncthreads();
        int add = 0;
        #pragma unroll
        for (int w = 0; w < 4; w++) if (w < wave) add += wsum[w];
        int chunk_total = wsum[0] + wsum[1] + wsum[2] + wsum[3];
        sv += add;
        if (i < NNODE) row_ptr[i+1] = run + sv;
        run += chunk_total;
        __syncthreads();
    }
}

__global__ __launch_bounds__(256) void k_fill(const int* __restrict__ src, const int* __restrict__ dst,
        const int* __restrict__ row_ptr, int* __restrict__ cursor, const float* __restrict__ dis,
        int* __restrict__ csr_src, float* __restrict__ csr_coef){
    int e = blockIdx.x*256 + threadIdx.x;
    if (e >= NEDGE) return;
    int s = src[e], d = dst[e];
    int pos = atomicAdd(&cursor[d], 1);
    int idx = row_ptr[d] + pos;
    csr_src[idx]  = s;
    csr_coef[idx] = dis[s] * dis[d];
}

// ---------------- aggregation: out[i] = relu(sum_in h[s]*coef + h[i]*dis[i]^2 + b) ----------------

template<int NF>   // F = NF*128
__global__ __launch_bounds__(128) void k_agg(const float* __restrict__ h, const int* __restrict__ rp,
        const int* __restrict__ cs, const float* __restrict__ cc, const float* __restrict__ dis,
        const float* __restrict__ bias, float* __restrict__ out){
    const int F = NF*128;
    int i = blockIdx.x; int tid = threadIdx.x;
    float acc[NF];
    #pragma unroll
    for (int j = 0; j < NF; j++) acc[j] = 0.f;
    int e0 = rp[i], e1 = rp[i+1];
    for (int e = e0; e < e1; e++){
        int s = cs[e]; float c = cc[e];
        const float* hs = h + (size_t)s*F;
        #pragma unroll
        for (int j = 0; j < NF; j++) acc[j] += hs[tid + j*128] * c;
    }
    float d = dis[i]; float d2 = d*d;
    const float* hi = h + (size_t)i*F;
    float* oi = out + (size_t)i*F;
    #pragma unroll
    for (int j = 0; j < NF; j++){
        float v = acc[j] + hi[tid + j*128]*d2 + bias[tid + j*128];
        oi[tid + j*128] = fmaxf(v, 0.f);
    }
}

// ---------------- small GEMM: C[M,ldn] = op(A[M,K]) @ B[K,ldn], tiles BM=32 BN=128 BK=32 ----------------

template<bool SQ, bool EPI>
__global__ __launch_bounds__(256) void gemm_small(const float* __restrict__ A, const float* __restrict__ B,
        const float* __restrict__ bias, float* __restrict__ C, int M, int K, int ldn){
    __shared__ float As[32][33];    // [k][m], padded
    __shared__ float Bs[32][128];   // [k][n]
    int row0 = blockIdx.x*32, col0 = blockIdx.y*128;
    int tid = threadIdx.x;
    int ty = tid >> 5, tx = tid & 31;     // 8 x 32 threads; micro-tile 4x4
    float acc[4][4] = {};
    for (int k0 = 0; k0 < K; k0 += 32){
        int ar = tid >> 3, ac = (tid & 7) << 2;
        float4 av = make_float4(0.f,0.f,0.f,0.f);
        int grow = row0 + ar;
        if (grow < M) av = *reinterpret_cast<const float4*>(A + (size_t)grow*K + k0 + ac);
        if (SQ){ av.x*=av.x; av.y*=av.y; av.z*=av.z; av.w*=av.w; }
        As[ac+0][ar] = av.x; As[ac+1][ar] = av.y; As[ac+2][ar] = av.z; As[ac+3][ar] = av.w;
        int c4 = (tid & 31) << 2;
        #pragma unroll
        for (int j = 0; j < 4; j++){
            int kb = (tid >> 5) + j*8;
            float4 bv = *reinterpret_cast<const float4*>(B + (size_t)(k0+kb)*ldn + col0 + c4);
            *reinterpret_cast<float4*>(&Bs[kb][c4]) = bv;
        }
        __syncthreads();
        #pragma unroll
        for (int k = 0; k < 32; k++){
            float a0 = As[k][ty*4+0], a1 = As[k][ty*4+1], a2 = As[k][ty*4+2], a3 = As[k][ty*4+3];
            float4 b = *reinterpret_cast<const float4*>(&Bs[k][tx<<2]);
            acc[0][0] += a0*b.x; acc[0][1] += a0*b.y; acc[0][2] += a0*b.z; acc[0][3] += a0*b.w;
            acc[1][0] += a1*b.x; acc[1][1] += a1*b.y; acc[1][2] += a1*b.z; acc[1][3] += a1*b.w;
            acc[2][0] += a2*b.x; acc[2][1] += a2*b.y; acc[2][2] += a2*b.z; acc[2][3] += a2*b.w;
            acc[3][0] += a3*b.x; acc[3][1] += a3*b.y; acc[3][2] += a3*b.z; acc[3][3] += a3*b.w;
        }
        __syncthreads();
    }
    #pragma unroll
    for (int mi = 0; mi < 4; mi++){
        int r = row0 + ty*4 + mi;
        if (r < M){
            int c = col0 + (tx << 2);
            float4 v = make_float4(acc[mi][0], acc[mi][1], acc[mi][2], acc[mi][3]);
            if (EPI){
                v.x = fmaxf(v.x + bias[c+0], 0.f);
                v.y = fmaxf(v.y + bias[c+1], 0.f);
                v.z = fmaxf(v.z + bias[c+2], 0.f);
                v.w = fmaxf(v.w + bias[c+3], 0.f);
            }
            *reinterpret_cast<float4*>(C + (size_t)r*ldn + c) = v;
        }
    }
}

// ---------------- split-bf16 conversion kernels ----------------

// elementwise: in[n] f32 -> hi,lo bf16 (hi = RTN(x), lo = RTN(x - hi))
__global__ __launch_bounds__(256) void k_split(const float* __restrict__ in,
        __hip_bfloat16* __restrict__ hi, __hip_bfloat16* __restrict__ lo, int n){
    int i = blockIdx.x*256 + threadIdx.x;
    if (i < n){
        float v = in[i];
        __hip_bfloat16 h = __float2bfloat16(v);
        hi[i] = h;
        lo[i] = __float2bfloat16(v - __bfloat162float(h));
    }
}

// W [128][10000] f32 -> WT_hi/WT_lo [10000][128] bf16 (transposed split)
__global__ __launch_bounds__(256) void k_splitT(const float* __restrict__ W,
        __hip_bfloat16* __restrict__ hiT, __hip_bfloat16* __restrict__ loT){
    __shared__ float t[32][33];
    int c0 = blockIdx.x*32, k0 = blockIdx.y*32;
    int tid = threadIdx.x;
    #pragma unroll
    for (int p = 0; p < 4; p++){
        int k = p*8 + (tid>>5), c = tid&31;
        float v = 0.f;
        if (c0 + c < NNODE) v = W[(size_t)(k0+k)*NNODE + c0 + c];
        t[k][c] = v;
    }
    __syncthreads();
    #pragma unroll
    for (int p = 0; p < 4; p++){
        int c = p*8 + (tid>>5), k = tid&31;
        if (c0 + c < NNODE){
            float v = t[k][c];
            __hip_bfloat16 h = __float2bfloat16(v);
            hiT[(size_t)(c0+c)*128 + k0 + k] = h;
            loT[(size_t)(c0+c)*128 + k0 + k] = __float2bfloat16(v - __bfloat162float(h));
        }
    }
}

// ---------------- big GEMM (MFMA split-bf16):
// C[M,Ncol] = sigmoid( (Ah+Al)[M,128] @ (Bh+Bl)^T[128,Ncol] + bias ), B stored [Ncol][128]
// 3-product: AhBh + AhBl + AlBh. Tiles BM=BN=128, BK=64, 4 waves (2x2 of 64x64).

#define LDK 72   // 64 + 8 pad bf16 (row stride 144 B, 16B multiple)

__global__ __launch_bounds__(256,2) void gemm_mfma(
        const __hip_bfloat16* __restrict__ Ah, const __hip_bfloat16* __restrict__ Al,
        const __hip_bfloat16* __restrict__ Bh, const __hip_bfloat16* __restrict__ Bl,
        const float* __restrict__ bias, float* __restrict__ C, int M, int Ncol){
    __shared__ __hip_bfloat16 As[2][128][LDK];
    __shared__ __hip_bfloat16 Bs[2][128][LDK];
    const int tid = threadIdx.x;
    const int row0 = blockIdx.x*128, col0 = blockIdx.y*128;
    const int lane = tid & 63, w = tid >> 6;
    const int wr = (w >> 1)*64, wc = (w & 1)*64;   // wave's 64x64 quadrant
    const int lr = lane & 15, lg = lane >> 4;

    f32x4 acc[4][4];
    #pragma unroll
    for (int i = 0; i < 4; i++)
        #pragma unroll
        for (int j = 0; j < 4; j++) acc[i][j] = (f32x4){0.f,0.f,0.f,0.f};

    for (int k0 = 0; k0 < 128; k0 += 64){
        // stage: per (operand,half) 128 rows x 64 k = 1024 16B-chunks; 4 chunks/thread each
        #pragma unroll
        for (int p = 0; p < 4; p++){
            int c = tid + p*256;
            int row = c >> 3, kc = (c & 7) << 3;
            int ga = row0 + row;
            uint4 vh = make_uint4(0u,0u,0u,0u), vl = vh;
            if (ga < M){
                vh = *reinterpret_cast<const uint4*>(Ah + (size_t)ga*128 + k0 + kc);
                vl = *reinterpret_cast<const uint4*>(Al + (size_t)ga*128 + k0 + kc);
            }
            *reinterpret_cast<uint4*>(&As[0][row][kc]) = vh;
            *reinterpret_cast<uint4*>(&As[1][row][kc]) = vl;
            int gb = col0 + row;
            uint4 wh = make_uint4(0u,0u,0u,0u), wl = wh;
            if (gb < Ncol){
                wh = *reinterpret_cast<const uint4*>(Bh + (size_t)gb*128 + k0 + kc);
                wl = *reinterpret_cast<const uint4*>(Bl + (size_t)gb*128 + k0 + kc);
            }
            *reinterpret_cast<uint4*>(&Bs[0][row][kc]) = wh;
            *reinterpret_cast<uint4*>(&Bs[1][row][kc]) = wl;
        }
        __syncthreads();
        #pragma unroll
        for (int kk = 0; kk < 64; kk += 32){
            bf16x8 a_h[4], a_l[4], b_h[4], b_l[4];
            const int ko = kk + lg*8;   // lane's 8 contiguous K
            #pragma unroll
            for (int rt = 0; rt < 4; rt++){
                a_h[rt] = *reinterpret_cast<const bf16x8*>(&As[0][wr + rt*16 + lr][ko]);
                a_l[rt] = *reinterpret_cast<const bf16x8*>(&As[1][wr + rt*16 + lr][ko]);
                b_h[rt] = *reinterpret_cast<const bf16x8*>(&Bs[0][wc + rt*16 + lr][ko]);
                b_l[rt] = *reinterpret_cast<const bf16x8*>(&Bs[1][wc + rt*16 + lr][ko]);
            }
            #pragma unroll
            for (int rt = 0; rt < 4; rt++)
                #pragma unroll
                for (int ct = 0; ct < 4; ct++){
                    acc[rt][ct] = __builtin_amdgcn_mfma_f32_16x16x32_bf16(a_h[rt], b_h[ct], acc[rt][ct], 0,0,0);
                    acc[rt][ct] = __builtin_amdgcn_mfma_f32_16x16x32_bf16(a_h[rt], b_l[ct], acc[rt][ct], 0,0,0);
                    acc[rt][ct] = __builtin_amdgcn_mfma_f32_16x16x32_bf16(a_l[rt], b_h[ct], acc[rt][ct], 0,0,0);
                }
        }
        __syncthreads();
    }
    // epilogue: D row = 4*lg + q, col = lr (within 16x16 frag)
    #pragma unroll
    for (int rt = 0; rt < 4; rt++){
        #pragma unroll
        for (int q = 0; q < 4; q++){
            int r = row0 + wr + rt*16 + lg*4 + q;
            if (r >= M) continue;
            float* crow = C + (size_t)r*Ncol;
            #pragma unroll
            for (int ct = 0; ct < 4; ct++){
                int cc = col0 + wc + ct*16 + lr;
                if (cc < Ncol) crow[cc] = sigf(acc[rt][ct][q] + bias[cc]);
            }
        }
    }
}

// ---------------- launch ----------------

extern "C" void kernel_launch(void* const* d_in, const int* in_sizes, int n_in,
                              void* d_out, int out_size, void* d_ws, size_t ws_size,
                              hipStream_t stream){
    const float* x   = (const float*)d_in[0];
    const int*   ei  = (const int*)d_in[1];
    const float* We1 = (const float*)d_in[2];
    const float* be1 = (const float*)d_in[3];
    const float* We2 = (const float*)d_in[4];
    const float* be2 = (const float*)d_in[5];
    const float* Wd1 = (const float*)d_in[6];
    const float* bd1 = (const float*)d_in[7];
    const float* Wd2 = (const float*)d_in[8];
    const float* bd2 = (const float*)d_in[9];
    const float* Wl  = (const float*)d_in[10];
    const float* bl  = (const float*)d_in[11];
    const float* Wf  = (const float*)d_in[12];
    const float* bf  = (const float*)d_in[13];
    const int* src = ei;
    const int* dst = ei + NEDGE;

    float* out        = (float*)d_out;
    float* struct_out = out;
    float* xhat_out   = out + (size_t)NNODE*NNODE;
    float* z_out      = xhat_out + (size_t)NNODE*512;

    // workspace carve (all offsets multiples of 64 B)
    int*   cnt      = (int*)d_ws;
    int*   cursor   = cnt + 10016;
    int*   row_ptr  = cursor + 10016;
    int*   csr_src  = row_ptr + 10016;
    float* csr_coef = (float*)(csr_src + NEDGE);
    float* dis      = csr_coef + NEDGE;
    float* h        = dis + 10016;
    float* t1       = h + (size_t)NNODE*512;
    float* hmid     = t1 + (size_t)NNODE*128;
    __hip_bfloat16* Ah = (__hip_bfloat16*)(hmid + (size_t)NNODE*128);
    __hip_bfloat16* Al = Ah + (size_t)NNODE*128;
    __hip_bfloat16* BhT = Al + (size_t)NNODE*128;
    __hip_bfloat16* BlT = BhT + (size_t)NNODE*128;

    hipMemsetAsync(cnt, 0, 2*10016*sizeof(int), stream);
    k_hist<<<1250,256,0,stream>>>(dst, cnt);
    k_scan<<<1,256,0,stream>>>(cnt, row_ptr, dis);
    k_fill<<<1250,256,0,stream>>>(src, dst, row_ptr, cursor, dis, csr_src, csr_coef);

    dim3 b(256), g1(313,1), g4(313,4);
    // encoder L1: h = x @ We1 ; t1 = relu(agg(h) + be1)
    gemm_small<false,false><<<g1,b,0,stream>>>(x, We1, nullptr, h, NNODE, 512, 128);
    k_agg<1><<<NNODE,128,0,stream>>>(h, row_ptr, csr_src, csr_coef, dis, be1, t1);
    // encoder L2 -> z
    gemm_small<false,false><<<g1,b,0,stream>>>(t1, We2, nullptr, h, NNODE, 128, 128);
    k_agg<1><<<NNODE,128,0,stream>>>(h, row_ptr, csr_src, csr_coef, dis, be2, z_out);
    // decoder L1
    gemm_small<false,false><<<g1,b,0,stream>>>(z_out, Wd1, nullptr, h, NNODE, 128, 128);
    k_agg<1><<<NNODE,128,0,stream>>>(h, row_ptr, csr_src, csr_coef, dis, bd1, t1);
    // decoder L2 -> x_hat
    gemm_small<false,false><<<g4,b,0,stream>>>(t1, Wd2, nullptr, h, NNODE, 128, 512);
    k_agg<4><<<NNODE,128,0,stream>>>(h, row_ptr, csr_src, csr_coef, dis, bd2, xhat_out);
    // link predictor hidden: hmid = relu((x_hat^2) @ Wl + bl)
    gemm_small<true,true><<<g1,b,0,stream>>>(xhat_out, Wl, bl, hmid, NNODE, 512, 128);

    // split conversions for the big MFMA GEMM
    k_split<<<(NNODE*128 + 255)/256,256,0,stream>>>(hmid, Ah, Al, NNODE*128);
    dim3 gt(313, 4);
    k_splitT<<<gt,b,0,stream>>>(Wf, BhT, BlT);

    // struct = sigmoid((Ah+Al) @ (BhT+BlT)^T + bf)
    dim3 gb(79,79);
    gemm_mfma<<<gb,b,0,stream>>>(Ah, Al, BhT, BlT, bf, struct_out, NNODE, NNODE);
}